// Round 10
// baseline (165.056 us; speedup 1.0000x reference)
//
#include <hip/hip_runtime.h>

typedef float f32x4 __attribute__((ext_vector_type(4)));
typedef short s16x8 __attribute__((ext_vector_type(8)));
typedef unsigned short u16;
typedef unsigned int u32;

// Problem constants
// B=4, T=320, U=80, D=512, INNER=512, VOCAB=6, MAX_RLE=50
// out: base [102400*6] then rle [102400*50], fp32.

__device__ __forceinline__ u16 f2bf(float f) {
  u32 u = __float_as_uint(f);
  u32 r = (u + 0x7FFFu + ((u >> 16) & 1u)) >> 16;  // RNE
  return (u16)r;
}

__device__ __forceinline__ u32 cvt_pk_bf16(float lo, float hi) {
  u32 r;
  asm("v_cvt_pk_bf16_f32 %0, %1, %2" : "=v"(r) : "v"(lo), "v"(hi));
  return r;
}

__device__ __forceinline__ float fast_tanh(float x) {
  float e = __expf(2.f * x);
  return __builtin_fmaf(-2.f, __builtin_amdgcn_rcpf(e + 1.f), 1.f);
}

// ---- fused prep: [0,400) cast X; [400,2448) pack W_f; [2448,2576) pack W_out + bias ----
__global__ void prep_all(const float* __restrict__ enc, const float* __restrict__ dec,
                         s16x8* __restrict__ Xb,
                         const float* __restrict__ Wf, u16* __restrict__ WfF,
                         const float* __restrict__ Wb, const float* __restrict__ bb,
                         const float* __restrict__ Wr, const float* __restrict__ br,
                         u16* __restrict__ WoF, float* __restrict__ bias_cat) {
  int bx = blockIdx.x;
  int tid = threadIdx.x;
  if (bx < 400) {
    int idx = bx * 256 + tid;  // 0..102399
    long e = (long)idx * 8;
    const float* src = (e < 655360) ? (enc + e) : (dec + (e - 655360));
    f32x4 a = *(const f32x4*)src;
    f32x4 b = *(const f32x4*)(src + 4);
    s16x8 o;
    o[0] = (short)f2bf(a[0]); o[1] = (short)f2bf(a[1]);
    o[2] = (short)f2bf(a[2]); o[3] = (short)f2bf(a[3]);
    o[4] = (short)f2bf(b[0]); o[5] = (short)f2bf(b[1]);
    o[6] = (short)f2bf(b[2]); o[7] = (short)f2bf(b[3]);
    Xb[idx] = o;
  } else if (bx < 2448) {
    int idx = (bx - 400) * 256 + tid;  // 0..524287
    int j = idx & 7;
    int lane = (idx >> 3) & 63;
    int kk = (idx >> 9) & 15;
    int nt = (idx >> 13) & 31;
    int part = idx >> 18;
    int n = nt * 16 + (lane & 15);
    int k = part * 512 + kk * 32 + ((lane >> 4) << 3) + j;
    WfF[idx] = f2bf(Wf[n * 1024 + k]);
  } else {
    int idx = (bx - 2448) * 256 + tid;  // 0..32767
    int j = idx & 7;
    int lane = (idx >> 3) & 63;
    int ks = (idx >> 9) & 15;
    int nt = idx >> 13;
    int v = nt * 16 + (lane & 15);
    int k = ks * 32 + ((lane >> 4) << 3) + j;
    float val = (v < 6) ? Wb[v * 512 + k] : (v < 56 ? Wr[(v - 6) * 512 + k] : 0.f);
    WoF[idx] = f2bf(val);
    if (bx == 2448 && tid < 64) {
      int vv = tid;
      bias_cat[vv] = (vv < 6) ? bb[vv] : (vv < 56 ? br[vv - 6] : 0.f);
    }
  }
}

// ---- E-GEMM: Ebf[1280][512] = enc*Wf[:, :512]^T + b_f ; Dc[320][512] = dec*Wf[:,512:]^T
__global__ __launch_bounds__(256) void egemm(const s16x8* __restrict__ Xb,
                                             const s16x8* __restrict__ WfF,
                                             const float* __restrict__ b_f,
                                             float* __restrict__ Ebf,
                                             float* __restrict__ Dc) {
  int ms = blockIdx.x >> 3;   // 0..24
  int ns = blockIdx.x & 7;    // 0..7
  int w = threadIdx.x >> 6, l = threadIdx.x & 63;
  int r0 = ms * 64 + w * 16;
  int part = (r0 >= 1280) ? 1 : 0;
  int n0 = ns * 64;
  int lrow = r0 + (l & 15);
  int khi = (l >> 4) << 3;  // 0,8,16,24
  f32x4 acc[4] = {};
#pragma unroll
  for (int kk = 0; kk < 16; ++kk) {
    s16x8 a = Xb[lrow * 64 + kk * 4 + (khi >> 3)];
#pragma unroll
    for (int nt = 0; nt < 4; ++nt) {
      int ntg = ns * 4 + nt;
      s16x8 bf = WfF[((part * 32 + ntg) * 16 + kk) * 64 + l];
      acc[nt] = __builtin_amdgcn_mfma_f32_16x16x32_bf16(a, bf, acc[nt], 0, 0, 0);
    }
  }
#pragma unroll
  for (int nt = 0; nt < 4; ++nt) {
    int n = n0 + nt * 16 + (l & 15);
    float bias = part ? 0.f : b_f[n];
#pragma unroll
    for (int q = 0; q < 4; ++q) {
      int row = r0 + ((l >> 4) << 2) + q;
      float val = acc[nt][q] + bias;
      if (part) Dc[(row - 1280) * 512 + n] = val;
      else      Ebf[row * 512 + n] = val;
    }
  }
}

// ---- ablation family. MODE 0: stores only. 1: +loads (kept alive, never used).
// 2: +tanh/cvt consuming loads. 3: full (== R9 kernel, real output).
// All modes share grid/addressing/epilogue so pairwise deltas isolate phases.
template <int MODE>
__global__ __launch_bounds__(320, 4) void joint_abl(const float* __restrict__ Ebf,
                                                    const float* __restrict__ Dc,
                                                    const s16x8* __restrict__ WoF,
                                                    const float* __restrict__ bias_cat,
                                                    float* __restrict__ out) {
  int bt = blockIdx.x;          // 0..1279
  int b = bt / 320;
  int tid = threadIdx.x;
  int w = tid >> 6;             // wave 0..4 -> u rows [16w, 16w+16)
  int l = tid & 63;
  int u_base = w * 16;
  int urow = u_base + (l & 15);
  int khi = (l >> 4) << 3;

  const float* dbase = Dc + (long)(b * 80 + urow) * 512 + khi;
  const float* ebase = Ebf + (long)bt * 512 + khi;

  float bias[4];
#pragma unroll
  for (int nt = 0; nt < 4; ++nt) bias[nt] = bias_cat[nt * 16 + (l & 15)];

  f32x4 acc[4] = {};

  if constexpr (MODE >= 1) {
    f32x4 dc0 = *(const f32x4*)(dbase);
    f32x4 dc1 = *(const f32x4*)(dbase + 4);
    f32x4 dc2 = *(const f32x4*)(dbase + 32);
    f32x4 dc3 = *(const f32x4*)(dbase + 36);
    f32x4 ec0 = *(const f32x4*)(ebase);
    f32x4 ec1 = *(const f32x4*)(ebase + 4);
    f32x4 ec2 = *(const f32x4*)(ebase + 32);
    f32x4 ec3 = *(const f32x4*)(ebase + 36);

#pragma unroll
    for (int hc = 0; hc < 8; ++hc) {
      s16x8 bfr[8];
#pragma unroll
      for (int kk2 = 0; kk2 < 2; ++kk2)
#pragma unroll
        for (int nt = 0; nt < 4; ++nt)
          bfr[kk2 * 4 + nt] = WoF[(nt * 16 + hc * 2 + kk2) * 64 + l];
      if constexpr (MODE == 1) {
        asm volatile("" :: "v"(bfr[0]), "v"(bfr[1]), "v"(bfr[2]), "v"(bfr[3]),
                          "v"(bfr[4]), "v"(bfr[5]), "v"(bfr[6]), "v"(bfr[7]));
      }

      f32x4 nd0, nd1, nd2, nd3, ne0, ne1, ne2, ne3;
      if (hc < 7) {
        const float* dp = dbase + (hc + 1) * 64;
        const float* ep = ebase + (hc + 1) * 64;
        nd0 = *(const f32x4*)(dp);      nd1 = *(const f32x4*)(dp + 4);
        nd2 = *(const f32x4*)(dp + 32); nd3 = *(const f32x4*)(dp + 36);
        ne0 = *(const f32x4*)(ep);      ne1 = *(const f32x4*)(ep + 4);
        ne2 = *(const f32x4*)(ep + 32); ne3 = *(const f32x4*)(ep + 36);
      }

      if constexpr (MODE >= 2) {
        float t[8];
#pragma unroll
        for (int j = 0; j < 4; ++j) {
          t[j]     = fast_tanh(ec0[j] + dc0[j]);
          t[j + 4] = fast_tanh(ec1[j] + dc1[j]);
        }
        union { s16x8 vv; u32 ww[4]; } ha;
#pragma unroll
        for (int k = 0; k < 4; ++k) ha.ww[k] = cvt_pk_bf16(t[2 * k], t[2 * k + 1]);
        s16x8 afr0 = ha.vv;
#pragma unroll
        for (int j = 0; j < 4; ++j) {
          t[j]     = fast_tanh(ec2[j] + dc2[j]);
          t[j + 4] = fast_tanh(ec3[j] + dc3[j]);
        }
#pragma unroll
        for (int k = 0; k < 4; ++k) ha.ww[k] = cvt_pk_bf16(t[2 * k], t[2 * k + 1]);
        s16x8 afr1 = ha.vv;

        if constexpr (MODE == 2) {
          asm volatile("" :: "v"(afr0), "v"(afr1),
                            "v"(bfr[0]), "v"(bfr[1]), "v"(bfr[2]), "v"(bfr[3]),
                            "v"(bfr[4]), "v"(bfr[5]), "v"(bfr[6]), "v"(bfr[7]));
        } else {
#pragma unroll
          for (int nt = 0; nt < 4; ++nt)
            acc[nt] = __builtin_amdgcn_mfma_f32_16x16x32_bf16(afr0, bfr[nt], acc[nt], 0, 0, 0);
#pragma unroll
          for (int nt = 0; nt < 4; ++nt)
            acc[nt] = __builtin_amdgcn_mfma_f32_16x16x32_bf16(afr1, bfr[4 + nt], acc[nt], 0, 0, 0);
        }
      } else {
        // MODE 1: current d/e otherwise dead -> keep the loads alive
        asm volatile("" :: "v"(dc0), "v"(dc1), "v"(dc2), "v"(dc3),
                          "v"(ec0), "v"(ec1), "v"(ec2), "v"(ec3));
      }

      if (hc < 7) {
        dc0 = nd0; dc1 = nd1; dc2 = nd2; dc3 = nd3;
        ec0 = ne0; ec1 = ne1; ec2 = ne2; ec3 = ne3;
      }
    }
  }

  // epilogue (identical across modes): C/D map row=(l>>4)*4+q, col=l&15
  long pbase = (long)bt * 80 + u_base;
#pragma unroll
  for (int nt = 0; nt < 4; ++nt) {
    int v = nt * 16 + (l & 15);
#pragma unroll
    for (int q = 0; q < 4; ++q) {
      int ur = ((l >> 4) << 2) + q;
      long p = pbase + ur;
      float val = acc[nt][q] + bias[nt];
      if (v < 6)       out[p * 6 + v] = val;
      else if (v < 56) out[614400 + p * 50 + (v - 6)] = val;
    }
  }
}

extern "C" void kernel_launch(void* const* d_in, const int* in_sizes, int n_in,
                              void* d_out, int out_size, void* d_ws, size_t ws_size,
                              hipStream_t stream) {
  (void)in_sizes; (void)n_in; (void)out_size; (void)ws_size;
  const float* enc = (const float*)d_in[0];
  const float* dec = (const float*)d_in[1];
  const float* Wf  = (const float*)d_in[2];
  const float* bf  = (const float*)d_in[3];
  const float* Wb  = (const float*)d_in[4];
  const float* bb  = (const float*)d_in[5];
  const float* Wr  = (const float*)d_in[6];
  const float* br  = (const float*)d_in[7];
  float* out = (float*)d_out;
  char* ws = (char*)d_ws;

  s16x8* Xb     = (s16x8*)(ws);               // 1,638,400 B
  u16*   WfF    = (u16*)(ws + 1638400);       // 1,048,576 B
  u16*   WoF    = (u16*)(ws + 2686976);       //    65,536 B
  float* biasC  = (float*)(ws + 2752512);     //       256 B
  float* Ebf    = (float*)(ws + 2752768);     // 2,621,440 B
  float* Dc     = (float*)(ws + 5374208);     //   655,360 B

  prep_all<<<2576, 256, 0, stream>>>(enc, dec, Xb, Wf, WfF, Wb, bb, Wr, br, WoF, biasC);
  egemm<<<200, 256, 0, stream>>>(Xb, (const s16x8*)WfF, bf, Ebf, Dc);
  // Ablation probes (out is fully overwritten by the final real dispatch)
  joint_abl<0><<<1280, 320, 0, stream>>>(Ebf, Dc, (const s16x8*)WoF, biasC, out);
  joint_abl<1><<<1280, 320, 0, stream>>>(Ebf, Dc, (const s16x8*)WoF, biasC, out);
  joint_abl<2><<<1280, 320, 0, stream>>>(Ebf, Dc, (const s16x8*)WoF, biasC, out);
  // Real kernel (R9 numerics, bit-identical output) — LAST
  joint_abl<3><<<1280, 320, 0, stream>>>(Ebf, Dc, (const s16x8*)WoF, biasC, out);
}

// Round 11
// 50.233 us; speedup vs baseline: 3.2858x; 3.2858x over previous
//
#include <hip/hip_runtime.h>

typedef float f32x4 __attribute__((ext_vector_type(4)));
typedef short s16x8 __attribute__((ext_vector_type(8)));
typedef unsigned short u16;
typedef unsigned int u32;

// Problem constants
// B=4, T=320, U=80, D=512, INNER=512, VOCAB=6, MAX_RLE=50
// out: base [102400*6] then rle [102400*50], fp32.

__device__ __forceinline__ u16 f2bf(float f) {
  u32 u = __float_as_uint(f);
  u32 r = (u + 0x7FFFu + ((u >> 16) & 1u)) >> 16;  // RNE
  return (u16)r;
}

__device__ __forceinline__ u32 cvt_pk_bf16(float lo, float hi) {
  u32 r;
  asm("v_cvt_pk_bf16_f32 %0, %1, %2" : "=v"(r) : "v"(lo), "v"(hi));
  return r;
}

__device__ __forceinline__ float fast_tanh(float x) {
  float e = __expf(2.f * x);
  return __builtin_fmaf(-2.f, __builtin_amdgcn_rcpf(e + 1.f), 1.f);
}

// async global->LDS DMA, 16B per lane (dest = wave-uniform base + lane*16, linear)
__device__ __forceinline__ void async16(const float* g, float* l) {
  __builtin_amdgcn_global_load_lds(
      (const __attribute__((address_space(1))) unsigned int*)g,
      (__attribute__((address_space(3))) unsigned int*)l, 16, 0, 0);
}

// ---- fused prep: [0,400) cast X; [400,2448) pack W_f; [2448,2576) pack W_out + bias ----
__global__ void prep_all(const float* __restrict__ enc, const float* __restrict__ dec,
                         s16x8* __restrict__ Xb,
                         const float* __restrict__ Wf, u16* __restrict__ WfF,
                         const float* __restrict__ Wb, const float* __restrict__ bb,
                         const float* __restrict__ Wr, const float* __restrict__ br,
                         u16* __restrict__ WoF, float* __restrict__ bias_cat) {
  int bx = blockIdx.x;
  int tid = threadIdx.x;
  if (bx < 400) {
    int idx = bx * 256 + tid;  // 0..102399
    long e = (long)idx * 8;
    const float* src = (e < 655360) ? (enc + e) : (dec + (e - 655360));
    f32x4 a = *(const f32x4*)src;
    f32x4 b = *(const f32x4*)(src + 4);
    s16x8 o;
    o[0] = (short)f2bf(a[0]); o[1] = (short)f2bf(a[1]);
    o[2] = (short)f2bf(a[2]); o[3] = (short)f2bf(a[3]);
    o[4] = (short)f2bf(b[0]); o[5] = (short)f2bf(b[1]);
    o[6] = (short)f2bf(b[2]); o[7] = (short)f2bf(b[3]);
    Xb[idx] = o;
  } else if (bx < 2448) {
    int idx = (bx - 400) * 256 + tid;  // 0..524287
    int j = idx & 7;
    int lane = (idx >> 3) & 63;
    int kk = (idx >> 9) & 15;
    int nt = (idx >> 13) & 31;
    int part = idx >> 18;
    int n = nt * 16 + (lane & 15);
    int k = part * 512 + kk * 32 + ((lane >> 4) << 3) + j;
    WfF[idx] = f2bf(Wf[n * 1024 + k]);
  } else {
    int idx = (bx - 2448) * 256 + tid;  // 0..32767
    int j = idx & 7;
    int lane = (idx >> 3) & 63;
    int ks = (idx >> 9) & 15;
    int nt = idx >> 13;
    int v = nt * 16 + (lane & 15);
    int k = ks * 32 + ((lane >> 4) << 3) + j;
    float val = (v < 6) ? Wb[v * 512 + k] : (v < 56 ? Wr[(v - 6) * 512 + k] : 0.f);
    WoF[idx] = f2bf(val);
    if (bx == 2448 && tid < 64) {
      int vv = tid;
      bias_cat[vv] = (vv < 6) ? bb[vv] : (vv < 56 ? br[vv - 6] : 0.f);
    }
  }
}

// ---- E-GEMM: Ebf[1280][512] = enc*Wf[:, :512]^T + b_f ; Dc[320][512] = dec*Wf[:,512:]^T
__global__ __launch_bounds__(256) void egemm(const s16x8* __restrict__ Xb,
                                             const s16x8* __restrict__ WfF,
                                             const float* __restrict__ b_f,
                                             float* __restrict__ Ebf,
                                             float* __restrict__ Dc) {
  int ms = blockIdx.x >> 3;   // 0..24
  int ns = blockIdx.x & 7;    // 0..7
  int w = threadIdx.x >> 6, l = threadIdx.x & 63;
  int r0 = ms * 64 + w * 16;
  int part = (r0 >= 1280) ? 1 : 0;
  int n0 = ns * 64;
  int lrow = r0 + (l & 15);
  int khi = (l >> 4) << 3;  // 0,8,16,24
  f32x4 acc[4] = {};
#pragma unroll
  for (int kk = 0; kk < 16; ++kk) {
    s16x8 a = Xb[lrow * 64 + kk * 4 + (khi >> 3)];
#pragma unroll
    for (int nt = 0; nt < 4; ++nt) {
      int ntg = ns * 4 + nt;
      s16x8 bf = WfF[((part * 32 + ntg) * 16 + kk) * 64 + l];
      acc[nt] = __builtin_amdgcn_mfma_f32_16x16x32_bf16(a, bf, acc[nt], 0, 0, 0);
    }
  }
#pragma unroll
  for (int nt = 0; nt < 4; ++nt) {
    int n = n0 + nt * 16 + (l & 15);
    float bias = part ? 0.f : b_f[n];
#pragma unroll
    for (int q = 0; q < 4; ++q) {
      int row = r0 + ((l >> 4) << 2) + q;
      float val = acc[nt][q] + bias;
      if (part) Dc[(row - 1280) * 512 + n] = val;
      else      Ebf[row * 512 + n] = val;
    }
  }
}

// ---- main: block = (bt-pair, u-half). 256 thr / 4 waves; wave w = n-tile w.
// Rows = 2 t's x NRH*16 u's. Per K-chunk (64): async-stage Dc[NRH*16][64] f32
// (global_load_lds, double-buffered), h = tanh(E+Dc) -> bf16 h_s (swizzled),
// barrier, MFMA (2 kk x 2*NRH m-tiles), barrier. Dc staged once serves BOTH t's.
template <int NRH>   // u-rows per t = NRH*16 (3 -> rows 0..47, 2 -> rows 48..79)
__device__ __forceinline__ void jbody(float* dcbuf, u32* h_s,
                                      const float* __restrict__ Ebf,
                                      const float* __restrict__ Dc,
                                      const s16x8* __restrict__ WoF,
                                      const float* __restrict__ bias_cat,
                                      float* __restrict__ out, int bt0, int u0) {
  int b = bt0 / 320;
  const float* DcB = Dc + (long)(b * 80 + u0) * 512;
  const float* Eb0 = Ebf + (long)bt0 * 512;
  const float* Eb1 = Eb0 + 512;
  int tid = threadIdx.x, w = tid >> 6, l = tid & 63;
  int k4 = tid & 15;
  int v = w * 16 + (l & 15);
  float bias_v = bias_cat[v];
  f32x4 acc[2 * NRH];
#pragma unroll
  for (int i = 0; i < 2 * NRH; ++i) acc[i] = f32x4{0.f, 0.f, 0.f, 0.f};

  // stage chunk 0 (c=0)
#pragma unroll
  for (int r = 0; r < NRH; ++r) {
    int idx = tid + r * 256;
    async16(DcB + (idx >> 4) * 512 + (idx & 15) * 4, dcbuf + idx * 4);
  }
  __syncthreads();

#pragma unroll
  for (int c = 0; c < 8; ++c) {
    float* cur = dcbuf + (c & 1) * (NRH * 1024);
    if (c < 7) {
      float* nxt = dcbuf + ((c + 1) & 1) * (NRH * 1024);
#pragma unroll
      for (int r = 0; r < NRH; ++r) {
        int idx = tid + r * 256;
        async16(DcB + (idx >> 4) * 512 + (c + 1) * 64 + (idx & 15) * 4,
                nxt + idx * 4);
      }
    }
    // bfr + E prefetch (consumed after the h-phase / immediately; small reg cost)
    s16x8 bfr0 = WoF[(w * 16 + c * 2 + 0) * 64 + l];
    s16x8 bfr1 = WoF[(w * 16 + c * 2 + 1) * 64 + l];
    f32x4 e0 = *(const f32x4*)(Eb0 + c * 64 + k4 * 4);
    f32x4 e1 = *(const f32x4*)(Eb1 + c * 64 + k4 * 4);

    // h-phase: 2*NRH rounds of 256 slots; slot -> (row, k4)
#pragma unroll
    for (int r2 = 0; r2 < 2 * NRH; ++r2) {
      int tt = r2 / NRH;
      int idx = tid + (r2 % NRH) * 256;   // dc slot (same bytes this thread staged)
      int ul = idx >> 4;
      f32x4 d = *(const f32x4*)(cur + idx * 4);
      f32x4 e = tt ? e1 : e0;
      float t0 = fast_tanh(e[0] + d[0]);
      float t1 = fast_tanh(e[1] + d[1]);
      float t2 = fast_tanh(e[2] + d[2]);
      float t3 = fast_tanh(e[3] + d[3]);
      u32 lo = cvt_pk_bf16(t0, t1);
      u32 hi = cvt_pk_bf16(t2, t3);
      int row = tt * (NRH * 16) + ul;
      u32* hp = h_s + row * 32 + (((k4 >> 1) ^ (row & 7)) << 2) + (k4 & 1) * 2;
      hp[0] = lo; hp[1] = hi;
    }
    __syncthreads();   // h_s ready (also drains c+1 DMA; counted-vmcnt refinement later)

    // MFMA: wave w = n-tile w; 2 kk-steps x 2*NRH m-tiles
#pragma unroll
    for (int kk = 0; kk < 2; ++kk) {
      s16x8 bf = kk ? bfr1 : bfr0;
#pragma unroll
      for (int mt = 0; mt < 2 * NRH; ++mt) {
        int row = mt * 16 + (l & 15);
        int u16i = (kk * 4 + (l >> 4)) ^ (row & 7);
        s16x8 a = *(const s16x8*)(h_s + row * 32 + u16i * 4);
        acc[mt] = __builtin_amdgcn_mfma_f32_16x16x32_bf16(a, bf, acc[mt], 0, 0, 0);
      }
    }
    __syncthreads();   // all h_s reads done before next chunk's writes
  }

  // epilogue: C/D map row=(l>>4)*4+q, col=l&15; m-tile mt -> (tt = mt/NRH, u-block mt%NRH)
#pragma unroll
  for (int mt = 0; mt < 2 * NRH; ++mt) {
    int tt = mt / NRH;
    long pbase = (long)(bt0 + tt) * 80 + u0 + (mt % NRH) * 16;
#pragma unroll
    for (int q = 0; q < 4; ++q) {
      int ur = ((l >> 4) << 2) + q;
      long p = pbase + ur;
      float val = acc[mt][q] + bias_v;
      if (v < 6)       out[p * 6 + v] = val;
      else if (v < 56) out[614400 + p * 50 + (v - 6)] = val;
    }
  }
}

// grid 1280: bid -> (pair = bid>>1 -> bt0 = pair*2, half = bid&1)
__global__ __launch_bounds__(256) void joint_main(const float* __restrict__ Ebf,
                                                  const float* __restrict__ Dc,
                                                  const s16x8* __restrict__ WoF,
                                                  const float* __restrict__ bias_cat,
                                                  float* __restrict__ out) {
  __shared__ __align__(16) float dcbuf[2][3072];   // 2 x [48][64] f32 (NRH=3 max)
  __shared__ __align__(16) u32 h_s[96 * 32];       // [96 rows][128B], 16B-unit swizzled
  int bid = blockIdx.x;
  int bt0 = (bid >> 1) * 2;
  int half = bid & 1;
  if (half) jbody<2>(&dcbuf[0][0], h_s, Ebf, Dc, WoF, bias_cat, out, bt0, 48);
  else      jbody<3>(&dcbuf[0][0], h_s, Ebf, Dc, WoF, bias_cat, out, bt0, 0);
}

extern "C" void kernel_launch(void* const* d_in, const int* in_sizes, int n_in,
                              void* d_out, int out_size, void* d_ws, size_t ws_size,
                              hipStream_t stream) {
  (void)in_sizes; (void)n_in; (void)out_size; (void)ws_size;
  const float* enc = (const float*)d_in[0];
  const float* dec = (const float*)d_in[1];
  const float* Wf  = (const float*)d_in[2];
  const float* bf  = (const float*)d_in[3];
  const float* Wb  = (const float*)d_in[4];
  const float* bb  = (const float*)d_in[5];
  const float* Wr  = (const float*)d_in[6];
  const float* br  = (const float*)d_in[7];
  float* out = (float*)d_out;
  char* ws = (char*)d_ws;

  s16x8* Xb     = (s16x8*)(ws);               // 1,638,400 B
  u16*   WfF    = (u16*)(ws + 1638400);       // 1,048,576 B
  u16*   WoF    = (u16*)(ws + 2686976);       //    65,536 B
  float* biasC  = (float*)(ws + 2752512);     //       256 B
  float* Ebf    = (float*)(ws + 2752768);     // 2,621,440 B
  float* Dc     = (float*)(ws + 5374208);     //   655,360 B
  // total 6,029,568 B of d_ws used

  prep_all<<<2576, 256, 0, stream>>>(enc, dec, Xb, Wf, WfF, Wb, bb, Wr, br, WoF, biasC);
  egemm<<<200, 256, 0, stream>>>(Xb, (const s16x8*)WfF, bf, Ebf, Dc);
  joint_main<<<1280, 256, 0, stream>>>(Ebf, Dc, (const s16x8*)WoF, biasC, out);
}

// Round 12
// 47.231 us; speedup vs baseline: 3.4947x; 1.0636x over previous
//
#include <hip/hip_runtime.h>

typedef float f32x4 __attribute__((ext_vector_type(4)));
typedef short s16x8 __attribute__((ext_vector_type(8)));
typedef unsigned short u16;
typedef unsigned int u32;

// Problem constants
// B=4, T=320, U=80, D=512, INNER=512, VOCAB=6, MAX_RLE=50
// out: base [102400*6] then rle [102400*50], fp32.

__device__ __forceinline__ u16 f2bf(float f) {
  u32 u = __float_as_uint(f);
  u32 r = (u + 0x7FFFu + ((u >> 16) & 1u)) >> 16;  // RNE
  return (u16)r;
}

__device__ __forceinline__ u32 cvt_pk_bf16(float lo, float hi) {
  u32 r;
  asm("v_cvt_pk_bf16_f32 %0, %1, %2" : "=v"(r) : "v"(lo), "v"(hi));
  return r;
}

__device__ __forceinline__ float fast_tanh(float x) {
  float e = __expf(2.f * x);
  return __builtin_fmaf(-2.f, __builtin_amdgcn_rcpf(e + 1.f), 1.f);
}

// async global->LDS DMA, 16B per lane (dest must equal wave-uniform base + lane*16;
// we pass base + tid*16 which satisfies that per wave)
__device__ __forceinline__ void async16(const float* g, float* l) {
  __builtin_amdgcn_global_load_lds(
      (const __attribute__((address_space(1))) unsigned int*)g,
      (__attribute__((address_space(3))) unsigned int*)l, 16, 0, 0);
}

// ---- fused prep: [0,400) cast X; [400,2448) pack W_f; [2448,2576) pack W_out + bias ----
__global__ void prep_all(const float* __restrict__ enc, const float* __restrict__ dec,
                         s16x8* __restrict__ Xb,
                         const float* __restrict__ Wf, u16* __restrict__ WfF,
                         const float* __restrict__ Wb, const float* __restrict__ bb,
                         const float* __restrict__ Wr, const float* __restrict__ br,
                         u16* __restrict__ WoF, float* __restrict__ bias_cat) {
  int bx = blockIdx.x;
  int tid = threadIdx.x;
  if (bx < 400) {
    int idx = bx * 256 + tid;  // 0..102399
    long e = (long)idx * 8;
    const float* src = (e < 655360) ? (enc + e) : (dec + (e - 655360));
    f32x4 a = *(const f32x4*)src;
    f32x4 b = *(const f32x4*)(src + 4);
    s16x8 o;
    o[0] = (short)f2bf(a[0]); o[1] = (short)f2bf(a[1]);
    o[2] = (short)f2bf(a[2]); o[3] = (short)f2bf(a[3]);
    o[4] = (short)f2bf(b[0]); o[5] = (short)f2bf(b[1]);
    o[6] = (short)f2bf(b[2]); o[7] = (short)f2bf(b[3]);
    Xb[idx] = o;
  } else if (bx < 2448) {
    int idx = (bx - 400) * 256 + tid;  // 0..524287
    int j = idx & 7;
    int lane = (idx >> 3) & 63;
    int kk = (idx >> 9) & 15;
    int nt = (idx >> 13) & 31;
    int part = idx >> 18;
    int n = nt * 16 + (lane & 15);
    int k = part * 512 + kk * 32 + ((lane >> 4) << 3) + j;
    WfF[idx] = f2bf(Wf[n * 1024 + k]);
  } else {
    int idx = (bx - 2448) * 256 + tid;  // 0..32767
    int j = idx & 7;
    int lane = (idx >> 3) & 63;
    int ks = (idx >> 9) & 15;
    int nt = idx >> 13;
    int v = nt * 16 + (lane & 15);
    int k = ks * 32 + ((lane >> 4) << 3) + j;
    float val = (v < 6) ? Wb[v * 512 + k] : (v < 56 ? Wr[(v - 6) * 512 + k] : 0.f);
    WoF[idx] = f2bf(val);
    if (bx == 2448 && tid < 64) {
      int vv = tid;
      bias_cat[vv] = (vv < 6) ? bb[vv] : (vv < 56 ? br[vv - 6] : 0.f);
    }
  }
}

// ---- E-GEMM: Ebf[1280][512] = enc*Wf[:, :512]^T + b_f ; Dc[320][512] = dec*Wf[:,512:]^T
__global__ __launch_bounds__(256) void egemm(const s16x8* __restrict__ Xb,
                                             const s16x8* __restrict__ WfF,
                                             const float* __restrict__ b_f,
                                             float* __restrict__ Ebf,
                                             float* __restrict__ Dc) {
  int ms = blockIdx.x >> 3;   // 0..24
  int ns = blockIdx.x & 7;    // 0..7
  int w = threadIdx.x >> 6, l = threadIdx.x & 63;
  int r0 = ms * 64 + w * 16;
  int part = (r0 >= 1280) ? 1 : 0;
  int n0 = ns * 64;
  int lrow = r0 + (l & 15);
  int khi = (l >> 4) << 3;  // 0,8,16,24
  f32x4 acc[4] = {};
#pragma unroll
  for (int kk = 0; kk < 16; ++kk) {
    s16x8 a = Xb[lrow * 64 + kk * 4 + (khi >> 3)];
#pragma unroll
    for (int nt = 0; nt < 4; ++nt) {
      int ntg = ns * 4 + nt;
      s16x8 bf = WfF[((part * 32 + ntg) * 16 + kk) * 64 + l];
      acc[nt] = __builtin_amdgcn_mfma_f32_16x16x32_bf16(a, bf, acc[nt], 0, 0, 0);
    }
  }
#pragma unroll
  for (int nt = 0; nt < 4; ++nt) {
    int n = n0 + nt * 16 + (l & 15);
    float bias = part ? 0.f : b_f[n];
#pragma unroll
    for (int q = 0; q < 4; ++q) {
      int row = r0 + ((l >> 4) << 2) + q;
      float val = acc[nt][q] + bias;
      if (part) Dc[(row - 1280) * 512 + n] = val;
      else      Ebf[row * 512 + n] = val;
    }
  }
}

// ---- main: block = (bt-pair, u-fifth): 2 t's x 16 u-rows. grid 3200, 256 thr / 4 waves
// (wave w = n-tile w). Per K-chunk (64): async-stage Dc[16][64] f32 (dbuf), h = tanh(E+Dc)
// for both t's (shared d!), write bf16 h_s (dbuf, swizzled), ONE barrier, MFMA (2kk x 2mt).
// Small LDS (16.4KB) + uniform blocks -> ~8 blocks/CU resident.
__global__ __launch_bounds__(256) void joint_main(const float* __restrict__ Ebf,
                                                  const float* __restrict__ Dc,
                                                  const s16x8* __restrict__ WoF,
                                                  const float* __restrict__ bias_cat,
                                                  float* __restrict__ out) {
  __shared__ __align__(16) float dcbuf[2][1024];  // [2][16 rows][64] f32
  __shared__ __align__(16) u32 h_s[2][32 * 32];   // [2][32 rows][128B], 16B-unit swizzle
  int bid = blockIdx.x;
  int pair = bid / 5, uf = bid - pair * 5;
  int bt0 = pair * 2;
  int b = pair / 160;
  int u0 = uf * 16;
  int tid = threadIdx.x, w = tid >> 6, l = tid & 63;
  int k4 = tid & 15;          // 16B k-slot
  int row16 = tid >> 4;       // u-row 0..15 this thread stages/computes

  const float* DcB = Dc + (long)(b * 80 + u0) * 512;
  const float* Eb0 = Ebf + (long)bt0 * 512;
  const float* Eb1 = Eb0 + 512;
  int v = w * 16 + (l & 15);
  float bias_v = bias_cat[v];
  f32x4 acc[2] = {};

  // prologue: stage chunk 0
  async16(DcB + row16 * 512 + k4 * 4, &dcbuf[0][tid * 4]);
  __syncthreads();

#pragma unroll
  for (int c = 0; c < 8; ++c) {
    float* cur = dcbuf[c & 1];
    if (c < 7)
      async16(DcB + row16 * 512 + (c + 1) * 64 + k4 * 4, &dcbuf[(c + 1) & 1][tid * 4]);
    s16x8 bfr0 = WoF[(w * 16 + c * 2 + 0) * 64 + l];
    s16x8 bfr1 = WoF[(w * 16 + c * 2 + 1) * 64 + l];
    f32x4 e0 = *(const f32x4*)(Eb0 + c * 64 + k4 * 4);
    f32x4 e1 = *(const f32x4*)(Eb1 + c * 64 + k4 * 4);

    // h-phase: one dcbuf read serves both t's
    f32x4 d = *(const f32x4*)(cur + tid * 4);
    u32* hcur = h_s[c & 1];
    {
      float t0 = fast_tanh(e0[0] + d[0]);
      float t1 = fast_tanh(e0[1] + d[1]);
      float t2 = fast_tanh(e0[2] + d[2]);
      float t3 = fast_tanh(e0[3] + d[3]);
      u32 lo = cvt_pk_bf16(t0, t1), hi = cvt_pk_bf16(t2, t3);
      int row = row16;  // tt=0
      u32* hp = hcur + row * 32 + (((k4 >> 1) ^ (row & 7)) << 2) + (k4 & 1) * 2;
      hp[0] = lo; hp[1] = hi;
    }
    {
      float t0 = fast_tanh(e1[0] + d[0]);
      float t1 = fast_tanh(e1[1] + d[1]);
      float t2 = fast_tanh(e1[2] + d[2]);
      float t3 = fast_tanh(e1[3] + d[3]);
      u32 lo = cvt_pk_bf16(t0, t1), hi = cvt_pk_bf16(t2, t3);
      int row = 16 + row16;  // tt=1
      u32* hp = hcur + row * 32 + (((k4 >> 1) ^ (row & 7)) << 2) + (k4 & 1) * 2;
      hp[0] = lo; hp[1] = hi;
    }
    __syncthreads();  // h_s[c&1] ready; also drains this chunk's DMA issue (c+1)

    // MFMA: wave w = n-tile w; 2 kk-steps x 2 m-tiles (t0-rows, t1-rows)
#pragma unroll
    for (int kk = 0; kk < 2; ++kk) {
      s16x8 bf = kk ? bfr1 : bfr0;
#pragma unroll
      for (int mt = 0; mt < 2; ++mt) {
        int row = mt * 16 + (l & 15);
        int u16i = (kk * 4 + (l >> 4)) ^ (row & 7);
        s16x8 a = *(const s16x8*)(hcur + row * 32 + u16i * 4);
        acc[mt] = __builtin_amdgcn_mfma_f32_16x16x32_bf16(a, bf, acc[mt], 0, 0, 0);
      }
    }
    // no trailing barrier: next chunk writes h_s[(c+1)&1] / dcbuf[(c+1)&1],
    // both last-touched before the PREVIOUS barrier (hazard-checked).
  }

  // epilogue: C/D map row=(l>>4)*4+q, col=l&15; m-tile mt = t index
#pragma unroll
  for (int mt = 0; mt < 2; ++mt) {
    long pbase = (long)(bt0 + mt) * 80 + u0;
#pragma unroll
    for (int q = 0; q < 4; ++q) {
      int ur = ((l >> 4) << 2) + q;
      long p = pbase + ur;
      float val = acc[mt][q] + bias_v;
      if (v < 6)       out[p * 6 + v] = val;
      else if (v < 56) out[614400 + p * 50 + (v - 6)] = val;
    }
  }
}

extern "C" void kernel_launch(void* const* d_in, const int* in_sizes, int n_in,
                              void* d_out, int out_size, void* d_ws, size_t ws_size,
                              hipStream_t stream) {
  (void)in_sizes; (void)n_in; (void)out_size; (void)ws_size;
  const float* enc = (const float*)d_in[0];
  const float* dec = (const float*)d_in[1];
  const float* Wf  = (const float*)d_in[2];
  const float* bf  = (const float*)d_in[3];
  const float* Wb  = (const float*)d_in[4];
  const float* bb  = (const float*)d_in[5];
  const float* Wr  = (const float*)d_in[6];
  const float* br  = (const float*)d_in[7];
  float* out = (float*)d_out;
  char* ws = (char*)d_ws;

  s16x8* Xb     = (s16x8*)(ws);               // 1,638,400 B
  u16*   WfF    = (u16*)(ws + 1638400);       // 1,048,576 B
  u16*   WoF    = (u16*)(ws + 2686976);       //    65,536 B
  float* biasC  = (float*)(ws + 2752512);     //       256 B
  float* Ebf    = (float*)(ws + 2752768);     // 2,621,440 B
  float* Dc     = (float*)(ws + 5374208);     //   655,360 B
  // total 6,029,568 B of d_ws used

  prep_all<<<2576, 256, 0, stream>>>(enc, dec, Xb, Wf, WfF, Wb, bb, Wr, br, WoF, biasC);
  egemm<<<200, 256, 0, stream>>>(Xb, (const s16x8*)WfF, bf, Ebf, Dc);
  joint_main<<<3200, 256, 0, stream>>>(Ebf, Dc, (const s16x8*)WoF, biasC, out);
}